// Round 11
// baseline (490.391 us; speedup 1.0000x reference)
//
#include <hip/hip_runtime.h>

#define T_STEPS 512

typedef __attribute__((ext_vector_type(8))) short s16x8;  // 8 bf16 (4 VGPRs)
typedef __attribute__((ext_vector_type(4))) float f32x4;  // MFMA C/D

__device__ __forceinline__ short f2bf(float v) {          // fp32 -> bf16 RNE
    unsigned u = __float_as_uint(v);
    return (short)((u + 0x7FFFu + ((u >> 16) & 1u)) >> 16);
}
__device__ __forceinline__ float bf2f(short b) {
    return __uint_as_float(((unsigned)(unsigned short)b) << 16);
}
// Fast transcendentals: v_exp_f32 (2^x) + v_rcp_f32 (r8: -118us vs precise div).
#define LOG2E 1.4426950408889634f
__device__ __forceinline__ float rcpf(float x)  { return __builtin_amdgcn_rcpf(x); }
__device__ __forceinline__ float ex2f(float x)  { return __builtin_amdgcn_exp2f(x); }
__device__ __forceinline__ float sigf(float x)  { return rcpf(1.f + ex2f(-LOG2E * x)); }
__device__ __forceinline__ float tanhf_(float x){ return 1.f - 2.f * rcpf(ex2f(2.f * LOG2E * x) + 1.f); }

// LDS-only barrier (r9: neutral vs __syncthreads, kept as strictly-less-wait).
#define BAR() do { asm volatile("s_waitcnt lgkmcnt(0)" ::: "memory"); \
                   __builtin_amdgcn_s_barrier(); } while (0)

// Block: 4 batches, 512 threads = 8 waves; grid = 256 -> 1 block/CU.
// r10 change: GANG-SPLIT BY LAYER, M=64/wave. The step is issue-serialized
// (r8 showed VALU cuts pay 1:1; r7/r9 stall-targeting paid 0), so remove
// instructions: all 8 waves previously read the SAME wave-invariant B frags
// (40 ds_read_b128/step). Now waves 0-3 own ALL of L0 (4 tiles = M=64,
// 12 MFMAs, read only {x,h0lo,h0hi}) and waves 4-7 own L1 (16 MFMAs, read
// {h0lo,h0hi,h1lo,h1hi}): 28 B-reads/step (-30%), same 112 MFMAs, better
// per-wave MFMA ILP (4 independent chains). Register cost (~140 VGPR) is
// free: 1 block/CU fixes occupancy at 8 waves; cap is 256 (launch_bounds).
// Phase 2 unchanged: gang A = 256 L0 cells dense, gang B = 256 L1 cells.
// B-col clamp: cols 0-3 real; lanes n16>=4 broadcast col 3 (garbage only in
// D-cols 4-15, never read). bB stride 176 shorts -> 2 req/bank (0 conflicts).
__global__ __launch_bounds__(512, 2)
void lstm2_mfma(const float* __restrict__ x,
                const float* __restrict__ Wih0, const float* __restrict__ Whh0,
                const float* __restrict__ bih0, const float* __restrict__ bhh0,
                const float* __restrict__ Wih1, const float* __restrict__ Whh1,
                const float* __restrict__ bih1, const float* __restrict__ bhh1,
                const float* __restrict__ Wfc,  const float* __restrict__ bfc,
                float* __restrict__ out)
{
    // merged B buffer, bf16, [parity][n(4)][k]: x 0..31 | h0 32..95 | h1 96..159
    __shared__ __align__(16) short bB[2][4][176];
    // gate buffers: [state*4 + batch] -> f32x4 (i,f,g,o), bias included (C-seed)
    __shared__ __align__(16) float gbuf0[256 * 4];   // L0 (gang A writes/reads)
    __shared__ __align__(16) float gbuf1[256 * 4];   // L1 (gang B writes/reads)

    const int tid  = threadIdx.x;
    const int w    = tid >> 6;       // wave 0..7
    const int lane = tid & 63;
    const int n16  = lane & 15;      // MFMA col (batch for n<4) / A-row m
    const int q4   = lane >> 4;      // quad: D-state-slot; A k-run
    const int b0   = blockIdx.x * 4;
    const bool gA  = (w < 4);        // gang A = L0, gang B = L1
    const int wg   = w & 3;          // wave id within gang

    // ---- A fragments: FOUR 16-row tiles of this gang's layer. Tile t row m
    //      -> gate m&3, state 16*wg + 4t + (m>>2). Gang A uses af[t*3+k]
    //      (K=96: x,h0lo,h0hi); gang B af[t*4+k] (K=128: h0lo,h0hi,h1lo,h1hi).
    s16x8 af[16];
    f32x4 bias[4];
#pragma unroll
    for (int t = 0; t < 4; ++t) {
        const int rowW = (n16 & 3) * 64 + 16 * wg + 4 * t + (n16 >> 2);
        if (gA) {
#pragma unroll
            for (int j = 0; j < 8; ++j) {
                af[t * 3 + 0][j] = f2bf(Wih0[rowW * 32 + q4 * 8 + j]);
                af[t * 3 + 1][j] = f2bf(Whh0[rowW * 64 + q4 * 8 + j]);
                af[t * 3 + 2][j] = f2bf(Whh0[rowW * 64 + 32 + q4 * 8 + j]);
            }
        } else {
#pragma unroll
            for (int j = 0; j < 8; ++j) {
                af[t * 4 + 0][j] = f2bf(Wih1[rowW * 64 + q4 * 8 + j]);
                af[t * 4 + 1][j] = f2bf(Wih1[rowW * 64 + 32 + q4 * 8 + j]);
                af[t * 4 + 2][j] = f2bf(Whh1[rowW * 64 + q4 * 8 + j]);
                af[t * 4 + 3][j] = f2bf(Whh1[rowW * 64 + 32 + q4 * 8 + j]);
            }
        }
        const int jl = 16 * wg + 4 * t + q4;    // state whose gates tile t holds
        const float* bi = gA ? bih0 : bih1;
        const float* bh = gA ? bhh0 : bhh1;
#pragma unroll
        for (int p_ = 0; p_ < 4; ++p_)
            bias[t][p_] = bi[p_ * 64 + jl] + bh[p_ * 64 + jl];
    }

    // ---- gate-buffer indices ----
    int gw[4];                                   // writes (lanes n16<4)
#pragma unroll
    for (int t = 0; t < 4; ++t) gw[t] = ((16 * wg + 4 * t + q4) * 4 + n16) * 4;
    const int cs  = 16 * wg + (lane >> 2);       // cell state 0..63
    const int cb  = lane & 3;                    // cell batch 0..3
    const int gri = 64 * wg + lane;              // == cs*4 + cb (b128 dense)

    // ---- B-read column clamp ----
    const int nB  = (n16 < 4) ? n16 : 3;

    // ---- x stagers: waves 0-1 (gang A). Wave w stages batches 2w, 2w+1;
    //      full-lane. 2-deep register pipeline (r9). ----
    const bool isx = (w < 2);
    const int  xb  = w * 2 + (lane >> 5);    // 0..3
    const int  xk  = lane & 31;
    const float* xp = x + ((size_t)(b0 + xb) * T_STEPS) * 32 + xk;

    // ---- init: zero B buffer; stage x(0); preload x(1) ----
    for (int i = tid; i < 2 * 4 * 176 / 2; i += 512) ((int*)bB)[i] = 0;
    __syncthreads();
    float xc = 0.f;
    if (isx) {
        bB[0][xb][xk] = f2bf(xp[0]);
        xc = xp[32];                 // x(1)
    }
    __syncthreads();

    float cst = 0.f;                 // fp32 cell state (this lane's cell)

    for (int it = 0; it <= T_STEPS; ++it) {
        const int p = it & 1;

        // commit x(it+1) (loaded last iter); issue x(it+2)
        if (isx && it + 1 < T_STEPS) bB[p ^ 1][xb][xk] = f2bf(xc);
        float xn = 0.f;
        if (isx && it + 2 < T_STEPS) xn = xp[(size_t)(it + 2) * 32];

        // ======== phase 1: gates via MFMA (gang-specialized B reads) ========
        const short* bp = &bB[p][nB][q4 * 8];
        f32x4 dd0, dd1, dd2, dd3;
        if (gA) {                    // L0: K=96, 3 frags, 12 MFMAs
            s16x8 t0 = *(const s16x8*)(bp);          // x[it]
            s16x8 t1 = *(const s16x8*)(bp + 32);     // h0 lo
            s16x8 t2 = *(const s16x8*)(bp + 64);     // h0 hi
            dd0 = __builtin_amdgcn_mfma_f32_16x16x32_bf16(af[0],  t0, bias[0], 0, 0, 0);
            dd1 = __builtin_amdgcn_mfma_f32_16x16x32_bf16(af[3],  t0, bias[1], 0, 0, 0);
            dd2 = __builtin_amdgcn_mfma_f32_16x16x32_bf16(af[6],  t0, bias[2], 0, 0, 0);
            dd3 = __builtin_amdgcn_mfma_f32_16x16x32_bf16(af[9],  t0, bias[3], 0, 0, 0);
            dd0 = __builtin_amdgcn_mfma_f32_16x16x32_bf16(af[1],  t1, dd0, 0, 0, 0);
            dd1 = __builtin_amdgcn_mfma_f32_16x16x32_bf16(af[4],  t1, dd1, 0, 0, 0);
            dd2 = __builtin_amdgcn_mfma_f32_16x16x32_bf16(af[7],  t1, dd2, 0, 0, 0);
            dd3 = __builtin_amdgcn_mfma_f32_16x16x32_bf16(af[10], t1, dd3, 0, 0, 0);
            dd0 = __builtin_amdgcn_mfma_f32_16x16x32_bf16(af[2],  t2, dd0, 0, 0, 0);
            dd1 = __builtin_amdgcn_mfma_f32_16x16x32_bf16(af[5],  t2, dd1, 0, 0, 0);
            dd2 = __builtin_amdgcn_mfma_f32_16x16x32_bf16(af[8],  t2, dd2, 0, 0, 0);
            dd3 = __builtin_amdgcn_mfma_f32_16x16x32_bf16(af[11], t2, dd3, 0, 0, 0);
            if (n16 < 4) {
                *(f32x4*)&gbuf0[gw[0]] = dd0;
                *(f32x4*)&gbuf0[gw[1]] = dd1;
                *(f32x4*)&gbuf0[gw[2]] = dd2;
                *(f32x4*)&gbuf0[gw[3]] = dd3;
            }
        } else {                     // L1: K=128, 4 frags, 16 MFMAs
            s16x8 t1 = *(const s16x8*)(bp + 32);     // h0 lo
            s16x8 t2 = *(const s16x8*)(bp + 64);     // h0 hi
            s16x8 t3 = *(const s16x8*)(bp + 96);     // h1 lo
            s16x8 t4 = *(const s16x8*)(bp + 128);    // h1 hi
            dd0 = __builtin_amdgcn_mfma_f32_16x16x32_bf16(af[0],  t1, bias[0], 0, 0, 0);
            dd1 = __builtin_amdgcn_mfma_f32_16x16x32_bf16(af[4],  t1, bias[1], 0, 0, 0);
            dd2 = __builtin_amdgcn_mfma_f32_16x16x32_bf16(af[8],  t1, bias[2], 0, 0, 0);
            dd3 = __builtin_amdgcn_mfma_f32_16x16x32_bf16(af[12], t1, bias[3], 0, 0, 0);
            dd0 = __builtin_amdgcn_mfma_f32_16x16x32_bf16(af[1],  t2, dd0, 0, 0, 0);
            dd1 = __builtin_amdgcn_mfma_f32_16x16x32_bf16(af[5],  t2, dd1, 0, 0, 0);
            dd2 = __builtin_amdgcn_mfma_f32_16x16x32_bf16(af[9],  t2, dd2, 0, 0, 0);
            dd3 = __builtin_amdgcn_mfma_f32_16x16x32_bf16(af[13], t2, dd3, 0, 0, 0);
            dd0 = __builtin_amdgcn_mfma_f32_16x16x32_bf16(af[2],  t3, dd0, 0, 0, 0);
            dd1 = __builtin_amdgcn_mfma_f32_16x16x32_bf16(af[6],  t3, dd1, 0, 0, 0);
            dd2 = __builtin_amdgcn_mfma_f32_16x16x32_bf16(af[10], t3, dd2, 0, 0, 0);
            dd3 = __builtin_amdgcn_mfma_f32_16x16x32_bf16(af[14], t3, dd3, 0, 0, 0);
            dd0 = __builtin_amdgcn_mfma_f32_16x16x32_bf16(af[3],  t4, dd0, 0, 0, 0);
            dd1 = __builtin_amdgcn_mfma_f32_16x16x32_bf16(af[7],  t4, dd1, 0, 0, 0);
            dd2 = __builtin_amdgcn_mfma_f32_16x16x32_bf16(af[11], t4, dd2, 0, 0, 0);
            dd3 = __builtin_amdgcn_mfma_f32_16x16x32_bf16(af[15], t4, dd3, 0, 0, 0);
            if (n16 < 4) {
                *(f32x4*)&gbuf1[gw[0]] = dd0;
                *(f32x4*)&gbuf1[gw[1]] = dd1;
                *(f32x4*)&gbuf1[gw[2]] = dd2;
                *(f32x4*)&gbuf1[gw[3]] = dd3;
            }
        }
        BAR();                       // gates + x visible

        // ======== phase 2: dense cells, gang-local gates ========
        if (gA) {
            if (it < T_STEPS) {      // L0 at step `it`: 256 cells, full-lane
                f32x4 g = *(const f32x4*)&gbuf0[gri * 4];
                float cc = sigf(g[1]) * cst + sigf(g[0]) * tanhf_(g[2]);
                cst = cc;
                bB[p ^ 1][cb][32 + cs] = f2bf(sigf(g[3]) * tanhf_(cc));
            }
        } else {
            if (it >= 1) {           // L1 at step `it-1`: 256 cells, full-lane
                f32x4 g = *(const f32x4*)&gbuf1[gri * 4];
                float cc = sigf(g[1]) * cst + sigf(g[0]) * tanhf_(g[2]);
                cst = cc;
                bB[p ^ 1][cb][96 + cs] = f2bf(sigf(g[3]) * tanhf_(cc));
            }
        }
        BAR();                       // h visible for next step
        xc = xn;
    }

    // ---- final FC on h1[T-1] (last L1 write: it=512, p=0 -> bB[1]) ----
    if (tid < 4) {
        float s = bfc[0];
#pragma unroll
        for (int k = 0; k < 64; ++k)
            s += bf2f(bB[1][tid][96 + k]) * Wfc[k];
        out[b0 + tid] = s;
    }
}

extern "C" void kernel_launch(void* const* d_in, const int* in_sizes, int n_in,
                              void* d_out, int out_size, void* d_ws, size_t ws_size,
                              hipStream_t stream) {
    const float* x    = (const float*)d_in[0];
    const float* Wih0 = (const float*)d_in[1];
    const float* Whh0 = (const float*)d_in[2];
    const float* bih0 = (const float*)d_in[3];
    const float* bhh0 = (const float*)d_in[4];
    const float* Wih1 = (const float*)d_in[5];
    const float* Whh1 = (const float*)d_in[6];
    const float* bih1 = (const float*)d_in[7];
    const float* bhh1 = (const float*)d_in[8];
    const float* Wfc  = (const float*)d_in[9];
    const float* bfc  = (const float*)d_in[10];
    float* out = (float*)d_out;

    const int B = out_size;            // 1024
    dim3 grid(B / 4), block(512);      // 256 blocks -> 1 per CU
    hipLaunchKernelGGL(lstm2_mfma, grid, block, 0, stream,
                       x, Wih0, Whh0, bih0, bhh0,
                       Wih1, Whh1, bih1, bhh1, Wfc, bfc, out);
}

// Round 12
// 479.828 us; speedup vs baseline: 1.0220x; 1.0220x over previous
//
#include <hip/hip_runtime.h>

#define T_STEPS 512

typedef __attribute__((ext_vector_type(8))) short s16x8;  // 8 bf16 (4 VGPRs)
typedef __attribute__((ext_vector_type(4))) float f32x4;  // MFMA C/D

__device__ __forceinline__ short f2bf(float v) {          // fp32 -> bf16 RNE
    unsigned u = __float_as_uint(v);
    return (short)((u + 0x7FFFu + ((u >> 16) & 1u)) >> 16);
}
__device__ __forceinline__ float bf2f(short b) {
    return __uint_as_float(((unsigned)(unsigned short)b) << 16);
}
// Fast transcendentals: v_exp_f32 (2^x) + v_rcp_f32 (r8: -118us vs precise div).
#define LOG2E 1.4426950408889634f
__device__ __forceinline__ float rcpf(float x)  { return __builtin_amdgcn_rcpf(x); }
__device__ __forceinline__ float ex2f(float x)  { return __builtin_amdgcn_exp2f(x); }
__device__ __forceinline__ float sigf(float x)  { return rcpf(1.f + ex2f(-LOG2E * x)); }
__device__ __forceinline__ float tanhf_(float x){ return 1.f - 2.f * rcpf(ex2f(2.f * LOG2E * x) + 1.f); }

// Block: 4 batches, 1024 threads = 16 waves; grid = 256 -> 1 block/CU.
// r11: 16-WAVE LEAN -- r3's proven wave geometry (M=16/wave: 1 tile/layer,
// 7 MFMAs, states 4w..4w+3) combined with r8's diets (merged-176 bB buffer:
// 5 B-reads/wave = 80/CU vs r3's 112; rcp/exp2 cells; bias C-seed).
// Rationale: per-CU instruction totals rule this kernel (r3/r6/r8 diets paid
// ~1:1; r7/r9 stall-targeting paid 0; r10 gang-split regressed with new
// conflicts -> reverted). The untested axis is issue parallelism: 4 waves/
// SIMD here vs r8's 2, at nearly the same lean budget.
// Phase 1: all 16 waves MFMA both layers' gates (7 MFMAs), publish to gbuf.
// Phase 2: waves 0-3 = 256 L0 cells dense, 4-7 = 256 L1 cells dense,
//          waves 8-11 stage x (r3's proven stager).
// B-col clamp: cols 0-3 real; lanes n16>=4 broadcast col 3 (garbage only in
// D-cols 4-15, never read). bB stride 176 shorts -> 2 req/bank (0 conflicts).
// waves_per_eu(4,4): pin 4 waves/EU -> 128-reg cap, demand ~90 -> no spill
// (r4 lesson: unpinned compiler squeezes to 64 and spills).
__global__ __launch_bounds__(1024) __attribute__((amdgpu_waves_per_eu(4, 4)))
void lstm2_mfma(const float* __restrict__ x,
                const float* __restrict__ Wih0, const float* __restrict__ Whh0,
                const float* __restrict__ bih0, const float* __restrict__ bhh0,
                const float* __restrict__ Wih1, const float* __restrict__ Whh1,
                const float* __restrict__ bih1, const float* __restrict__ bhh1,
                const float* __restrict__ Wfc,  const float* __restrict__ bfc,
                float* __restrict__ out)
{
    // merged B buffer, bf16, [parity][n(4)][k]: x 0..31 | h0 32..95 | h1 96..159
    __shared__ __align__(16) short bB[2][4][176];
    // gate buffers: [state*4 + batch] -> f32x4 (i,f,g,o), bias included (C-seed)
    __shared__ __align__(16) float gbuf0[256 * 4];   // L0
    __shared__ __align__(16) float gbuf1[256 * 4];   // L1

    const int tid  = threadIdx.x;
    const int w    = tid >> 6;       // wave 0..15
    const int lane = tid & 63;
    const int n16  = lane & 15;      // MFMA col (batch for n<4) / A-row m
    const int q4   = lane >> 4;      // quad: D-state-slot; A k-run
    const int b0   = blockIdx.x * 4;

    // ---- A fragments: ONE 16-row tile per layer (r3 geometry). Row m ->
    //      gate m&3, state 4w + (m>>2). ----
    const int rowW = (n16 & 3) * 64 + 4 * w + (n16 >> 2);
    s16x8 a0, a1, a2;        // L0: K=96  {x, h0_lo, h0_hi}
    s16x8 e0, e1, e2, e3;    // L1: K=128 {h0_lo, h0_hi, h1_lo, h1_hi}
#pragma unroll
    for (int j = 0; j < 8; ++j) {
        a0[j] = f2bf(Wih0[rowW * 32 + q4 * 8 + j]);
        a1[j] = f2bf(Whh0[rowW * 64 + q4 * 8 + j]);
        a2[j] = f2bf(Whh0[rowW * 64 + 32 + q4 * 8 + j]);
        e0[j] = f2bf(Wih1[rowW * 64 + q4 * 8 + j]);
        e1[j] = f2bf(Wih1[rowW * 64 + 32 + q4 * 8 + j]);
        e2[j] = f2bf(Whh1[rowW * 64 + q4 * 8 + j]);
        e3[j] = f2bf(Whh1[rowW * 64 + 32 + q4 * 8 + j]);
    }

    // ---- bias as MFMA C-seed: reg p = gate p of state jL, all cols ----
    const int jL = 4 * w + q4;
    f32x4 bias0, bias1;
#pragma unroll
    for (int p_ = 0; p_ < 4; ++p_) {
        bias0[p_] = bih0[p_ * 64 + jL] + bhh0[p_ * 64 + jL];
        bias1[p_] = bih1[p_ * 64 + jL] + bhh1[p_ * 64 + jL];
    }

    // ---- gate-buffer indices (r2-proven) ----
    const int gwi = (jL * 4 + n16) * 4;      // write (lanes n16<4)
    const int cw  = w & 3;                   // cell sub-wave (waves 0..7)
    const int cs  = 16 * cw + (lane >> 2);   // cell state 0..63
    const int cb  = lane & 3;                // cell batch 0..3
    const int gri = 64 * cw + lane;          // == cs*4 + cb (consecutive b128)

    // ---- B-read column clamp ----
    const int nB  = (n16 < 4) ? n16 : 3;

    // ---- x stagers: waves 8..11, lanes 4<=n16<12 (r3-proven). Wave 8+b
    //      stages batch b's 32 x values. ----
    const bool isx = (w >= 8) && (w < 12) && (n16 >= 4) && (n16 < 12);
    const int  xb  = (w - 8) & 3;
    const int  xk  = q4 * 8 + ((n16 - 4) & 7);           // 0..31
    const float* xp = x + ((size_t)(b0 + xb) * T_STEPS) * 32 + xk;

    // ---- init: zero B buffer; stage x_0 ----
    for (int i = tid; i < 2 * 4 * 176 / 2; i += 1024) ((int*)bB)[i] = 0;
    __syncthreads();
    if (isx) bB[0][xb][xk] = f2bf(xp[0]);
    __syncthreads();

    float cst = 0.f;                 // fp32 cell state (waves 0-3: L0, 4-7: L1)

    for (int it = 0; it <= T_STEPS; ++it) {
        const int p = it & 1;

        float xpre = 0.f;
        const bool havex = isx && (it + 1 < T_STEPS);
        if (havex) xpre = xp[(size_t)(it + 1) * 32];

        // ======== phase 1: gates via MFMA (all 16 waves), 5 B-frag reads ========
        const short* bp = &bB[p][nB][q4 * 8];
        s16x8 t0 = *(const s16x8*)(bp);          // x[it]
        s16x8 t1 = *(const s16x8*)(bp + 32);     // h0 lo
        s16x8 t2 = *(const s16x8*)(bp + 64);     // h0 hi
        s16x8 t3 = *(const s16x8*)(bp + 96);     // h1 lo
        s16x8 t4 = *(const s16x8*)(bp + 128);    // h1 hi

        f32x4 d0 = __builtin_amdgcn_mfma_f32_16x16x32_bf16(a0, t0, bias0, 0, 0, 0);
        d0 = __builtin_amdgcn_mfma_f32_16x16x32_bf16(a1, t1, d0, 0, 0, 0);
        d0 = __builtin_amdgcn_mfma_f32_16x16x32_bf16(a2, t2, d0, 0, 0, 0);
        f32x4 d1 = __builtin_amdgcn_mfma_f32_16x16x32_bf16(e0, t1, bias1, 0, 0, 0);
        d1 = __builtin_amdgcn_mfma_f32_16x16x32_bf16(e1, t2, d1, 0, 0, 0);
        d1 = __builtin_amdgcn_mfma_f32_16x16x32_bf16(e2, t3, d1, 0, 0, 0);
        d1 = __builtin_amdgcn_mfma_f32_16x16x32_bf16(e3, t4, d1, 0, 0, 0);

        if (n16 < 4) {               // publish gate vectors (2 b128, 16 lanes)
            *(f32x4*)&gbuf0[gwi] = d0;
            *(f32x4*)&gbuf1[gwi] = d1;
        }
        __syncthreads();             // gates visible

        // ======== phase 2: dense cells (waves 0..7) + x stage (8..11) ========
        if (w < 4) {
            if (it < T_STEPS) {      // L0 at step `it`: 256 cells, full-lane
                f32x4 g = *(const f32x4*)&gbuf0[gri * 4];
                float cc = sigf(g[1]) * cst + sigf(g[0]) * tanhf_(g[2]);
                cst = cc;
                bB[p ^ 1][cb][32 + cs] = f2bf(sigf(g[3]) * tanhf_(cc));
            }
        } else if (w < 8) {
            if (it >= 1) {           // L1 at step `it-1`: 256 cells, full-lane
                f32x4 g = *(const f32x4*)&gbuf1[gri * 4];
                float cc = sigf(g[1]) * cst + sigf(g[0]) * tanhf_(g[2]);
                cst = cc;
                bB[p ^ 1][cb][96 + cs] = f2bf(sigf(g[3]) * tanhf_(cc));
            }
        }
        if (havex) bB[p ^ 1][xb][xk] = f2bf(xpre);
        __syncthreads();             // h + x visible for next step
    }

    // ---- final FC on h1[T-1] (last L1 write: it=512, p=0 -> bB[1]) ----
    if (tid < 4) {
        float s = bfc[0];
#pragma unroll
        for (int k = 0; k < 64; ++k)
            s += bf2f(bB[1][tid][96 + k]) * Wfc[k];
        out[b0 + tid] = s;
    }
}

extern "C" void kernel_launch(void* const* d_in, const int* in_sizes, int n_in,
                              void* d_out, int out_size, void* d_ws, size_t ws_size,
                              hipStream_t stream) {
    const float* x    = (const float*)d_in[0];
    const float* Wih0 = (const float*)d_in[1];
    const float* Whh0 = (const float*)d_in[2];
    const float* bih0 = (const float*)d_in[3];
    const float* bhh0 = (const float*)d_in[4];
    const float* Wih1 = (const float*)d_in[5];
    const float* Whh1 = (const float*)d_in[6];
    const float* bih1 = (const float*)d_in[7];
    const float* bhh1 = (const float*)d_in[8];
    const float* Wfc  = (const float*)d_in[9];
    const float* bfc  = (const float*)d_in[10];
    float* out = (float*)d_out;

    const int B = out_size;            // 1024
    dim3 grid(B / 4), block(1024);     // 256 blocks -> 1 per CU, 16 waves
    hipLaunchKernelGGL(lstm2_mfma, grid, block, 0, stream,
                       x, Wih0, Whh0, bih0, bhh0,
                       Wih1, Whh1, bih1, bhh1, Wfc, bfc, out);
}